// Round 13
// baseline (80.312 us; speedup 1.0000x reference)
//
#include <hip/hip_runtime.h>
#include <hip/hip_bf16.h>

typedef __bf16 bf16x8 __attribute__((ext_vector_type(8)));
typedef float f32x4 __attribute__((ext_vector_type(4)));
typedef unsigned short ushort4v __attribute__((ext_vector_type(4)));
typedef unsigned short ushort8v __attribute__((ext_vector_type(8)));

#define B_  16
#define C_  256
#define HW_ 4096
#define E_  8

__device__ inline unsigned short f2bf(float f) {
    unsigned int b = __builtin_bit_cast(unsigned int, f);
    b += 0x7FFFu + ((b >> 16) & 1u);   // RNE (inputs finite)
    return (unsigned short)(b >> 16);
}

// ---------------- K1: pooled[b][c] = mean_{h,w} inputs[b,c,h,w] ----------------
__global__ __launch_bounds__(256) void k_pool(const float* __restrict__ in,
                                              float* __restrict__ pooled) {
    int bc = blockIdx.x;
    const float* p = in + (size_t)bc * HW_;
    int t = threadIdx.x;
    float s = 0.f;
#pragma unroll
    for (int i = 0; i < 4; i++) {
        float4 v = *reinterpret_cast<const float4*>(p + (size_t)(t + i * 256) * 4);
        s += v.x + v.y + v.z + v.w;
    }
#pragma unroll
    for (int off = 32; off; off >>= 1) s += __shfl_down(s, off, 64);
    __shared__ float part[4];
    if ((t & 63) == 0) part[t >> 6] = s;
    __syncthreads();
    if (t == 0) pooled[bc] = (part[0] + part[1] + part[2] + part[3]) * (1.0f / HW_);
}

// ------- K2: gates + Weff slice (identity folded in) + biasE -------------------
__global__ __launch_bounds__(256) void k_wg(const float* __restrict__ pooled,
                                            const float* __restrict__ Wr,
                                            const float* __restrict__ br,
                                            const float* __restrict__ Wexp,
                                            const float* __restrict__ bexp,
                                            unsigned short* __restrict__ Weff,
                                            float* __restrict__ biasE) {
    __shared__ float pooledS[C_];      // 1 KB
    __shared__ float wrs[C_ * E_];     // 8 KB
    __shared__ float lgp[64];
    __shared__ float gL[E_];
    const int t = threadIdx.x;
    const int b = blockIdx.y, dblk = blockIdx.x;

    pooledS[t] = pooled[b * C_ + t];
#pragma unroll
    for (int i = 0; i < 2; ++i)
        reinterpret_cast<float4*>(wrs)[t + i * 256] =
            reinterpret_cast<const float4*>(Wr)[t + i * 256];
    __syncthreads();
    if (t < 64) {
        const int e = t & 7, seg = t >> 3;
        float s = 0.f;
#pragma unroll
        for (int c = seg * 32; c < seg * 32 + 32; ++c)
            s += pooledS[c] * wrs[c * E_ + e];
        lgp[t] = s;
    }
    __syncthreads();
    if (t == 0) {
        float w[E_];
        float m = -1e30f;
#pragma unroll
        for (int e = 0; e < E_; ++e) {
            float s = br[e];
#pragma unroll
            for (int k = 0; k < 8; ++k) s += lgp[k * 8 + e];
            w[e] = s; m = fmaxf(m, s);
        }
        float sum = 0.f;
#pragma unroll
        for (int e = 0; e < E_; ++e) { w[e] = __expf(w[e] - m); sum += w[e]; }
        float inv = 1.f / sum;
#pragma unroll
        for (int e = 0; e < E_; ++e) w[e] *= inv;
        int i0 = 0;
#pragma unroll
        for (int e = 1; e < E_; ++e) if (w[e] > w[i0]) i0 = e;
        int i1 = -1;
#pragma unroll
        for (int e = 0; e < E_; ++e) {
            if (e == i0) continue;
            if (i1 < 0 || w[e] > w[i1]) i1 = e;
        }
#pragma unroll
        for (int e = 0; e < E_; ++e)
            gL[e] = (e == i0 || e == i1) ? w[e] : 0.f;
    }
    __syncthreads();
    if (dblk == 0) {
        float s = 0.f;
#pragma unroll
        for (int e = 0; e < E_; ++e) s += gL[e] * bexp[e * C_ + t];
        biasE[b * C_ + t] = s;
    }
    const int dloc = t >> 5, cq = t & 31;
    const int d = dblk * 8 + dloc;
#pragma unroll
    for (int half = 0; half < 2; half++) {
        const int c = (cq + half * 32) * 4;
        float4 a = {0.f, 0.f, 0.f, 0.f};
#pragma unroll
        for (int e = 0; e < E_; e++) {
            float ge = gL[e];
            if (ge != 0.f) {
                float4 wv = *reinterpret_cast<const float4*>(
                    Wexp + ((size_t)(e * C_ + d)) * C_ + c);
                a.x += ge * wv.x; a.y += ge * wv.y;
                a.z += ge * wv.z; a.w += ge * wv.w;
            }
        }
        // fold identity: W' = Weff + I
        const int diff = d - c;
        if (diff == 0) a.x += 1.f;
        else if (diff == 1) a.y += 1.f;
        else if (diff == 2) a.z += 1.f;
        else if (diff == 3) a.w += 1.f;
        ushort4v o = { f2bf(a.x), f2bf(a.y), f2bf(a.z), f2bf(a.w) };
        *reinterpret_cast<ushort4v*>(Weff + ((size_t)(b * C_ + d)) * C_ + c) = o;
    }
}

// ---------------- K3: fused  out[b] = W'[b] @ x + biasE[b] ---------------------
// v4: N-tile 32, 256 threads (4 waves), full K=256 in LDS (17 KB) -> 8 blocks/CU.
// Grid 2048 blocks. Wave w owns d in [w*64, w*64+64): acc[4][2] (32 VGPR).
// Barrier-free direct-transpose staging (one barrier total); setprio on MFMA.
__global__ __launch_bounds__(256, 8) void k_fused(const float* __restrict__ in,
                                                  const unsigned short* __restrict__ Weff,
                                                  const float* __restrict__ biasE,
                                                  float* __restrict__ out) {
    __shared__ unsigned short Bs[32 * 256];   // 16 KB [p][c] bf16, chunk-XOR-swizzled
    __shared__ float biasS[C_];               // 1 KB

    const int t  = threadIdx.x;
    const int b  = blockIdx.y;
    const int n0 = blockIdx.x * 32;
    const int lane = t & 63, w = t >> 6;      // w in 0..3
    const int kg = lane >> 4, lr = lane & 15;
    const float* Xb = in + ((size_t)b * C_) * HW_ + n0;
    const unsigned short* Ab = Weff + (size_t)b * C_ * C_;

    biasS[t] = biasE[b * C_ + t];

    // ---- stage: 32 units of (8c x 32p); unit u = it*4 + w ----
    {
        const int dc = (lane >> 4) * 2;        // 0,2,4,6
        const int pl = (lane & 15) * 2;        // 0..30
#pragma unroll
        for (int it = 0; it < 8; ++it) {
            const int c_oct = it * 4 + w;      // logical chunk (c>>3), wave-uniform
            const int c = c_oct * 8 + dc;
            const int p = pl;
            const float* s = Xb + (size_t)c * HW_ + p;
            float2 v0 = *reinterpret_cast<const float2*>(s);        // (c,   p/p+1)
            float2 v1 = *reinterpret_cast<const float2*>(s + HW_);  // (c+1, p/p+1)
            unsigned int ue = (unsigned int)f2bf(v0.x) | ((unsigned int)f2bf(v1.x) << 16);
            unsigned int uo = (unsigned int)f2bf(v0.y) | ((unsigned int)f2bf(v1.y) << 16);
            const int cse = c_oct ^ (p & 7);
            const int cso = c_oct ^ ((p + 1) & 7);
            *reinterpret_cast<unsigned int*>(&Bs[p * 256 + cse * 8 + dc]) = ue;
            *reinterpret_cast<unsigned int*>(&Bs[(p + 1) * 256 + cso * 8 + dc]) = uo;
        }
    }
    __syncthreads();

    // ---- acc init: bias[d] splat (d = w*64 + fd*16 + lr) ----
    f32x4 acc[4][2];
#pragma unroll
    for (int fd = 0; fd < 4; ++fd) {
        const float bias = biasS[w * 64 + fd * 16 + lr];
#pragma unroll
        for (int pf = 0; pf < 2; ++pf)
            acc[fd][pf] = (f32x4){bias, bias, bias, bias};
    }

    // ---- MFMA main loop: 8 k-frags; W-frags from L2-resident Weff ----
    __builtin_amdgcn_s_setprio(1);
#pragma unroll
    for (int kf = 0; kf < 8; ++kf) {
        bf16x8 wf[4];
#pragma unroll
        for (int fd = 0; fd < 4; ++fd) {
            const int row = w * 64 + fd * 16 + lr;
            wf[fd] = __builtin_bit_cast(bf16x8,
                *reinterpret_cast<const ushort8v*>(
                    &Ab[(size_t)row * C_ + kf * 32 + kg * 8]));
        }
#pragma unroll
        for (int pf = 0; pf < 2; ++pf) {
            const int p = pf * 16 + lr;
            const int cc = (kf * 4 + kg) ^ (p & 7);
            bf16x8 xf = __builtin_bit_cast(bf16x8,
                *reinterpret_cast<const ushort8v*>(&Bs[p * 256 + cc * 8]));
#pragma unroll
            for (int fd = 0; fd < 4; ++fd)
                acc[fd][pf] = __builtin_amdgcn_mfma_f32_16x16x32_bf16(
                    xf, wf[fd], acc[fd][pf], 0, 0, 0);
        }
    }
    __builtin_amdgcn_s_setprio(0);

    // ---- store: lane holds 4 consecutive p at one d -> float4 ----
    float* outB = out + ((size_t)b * C_) * HW_ + n0;
#pragma unroll
    for (int fd = 0; fd < 4; ++fd) {
        const int row = w * 64 + fd * 16 + lr;
        float* orow = outB + (size_t)row * HW_;
#pragma unroll
        for (int pf = 0; pf < 2; ++pf) {
            *reinterpret_cast<f32x4*>(&orow[pf * 16 + kg * 4]) = acc[fd][pf];
        }
    }
}

extern "C" void kernel_launch(void* const* d_in, const int* in_sizes, int n_in,
                              void* d_out, int out_size, void* d_ws, size_t ws_size,
                              hipStream_t stream) {
    const float* in   = (const float*)d_in[0];
    const float* Wr   = (const float*)d_in[1];
    const float* br   = (const float*)d_in[2];
    const float* Wexp = (const float*)d_in[3];
    const float* bexp = (const float*)d_in[4];
    float* out = (float*)d_out;
    char* ws = (char*)d_ws;

    float* pooled         = (float*)(ws);                    // 16 KB
    float* biasE          = (float*)(ws + 0x11000);          // 16 KB
    unsigned short* Weff  = (unsigned short*)(ws + 0x20000); // 2 MB

    hipLaunchKernelGGL(k_pool,  dim3(B_ * C_), dim3(256), 0, stream, in, pooled);
    hipLaunchKernelGGL(k_wg,    dim3(32, B_),  dim3(256), 0, stream,
                       pooled, Wr, br, Wexp, bexp, Weff, biasE);
    hipLaunchKernelGGL(k_fused, dim3(HW_ / 32, B_), dim3(256), 0, stream,
                       in, Weff, biasE, out);
}

// Round 14
// 67.232 us; speedup vs baseline: 1.1945x; 1.1945x over previous
//
#include <hip/hip_runtime.h>
#include <hip/hip_bf16.h>

typedef __bf16 bf16x8 __attribute__((ext_vector_type(8)));
typedef float f32x4 __attribute__((ext_vector_type(4)));
typedef unsigned short ushort4v __attribute__((ext_vector_type(4)));
typedef unsigned short ushort8v __attribute__((ext_vector_type(8)));

#define B_  16
#define C_  256
#define HW_ 4096
#define E_  8

__device__ inline unsigned short f2bf(float f) {
    unsigned int b = __builtin_bit_cast(unsigned int, f);
    b += 0x7FFFu + ((b >> 16) & 1u);   // RNE (inputs finite)
    return (unsigned short)(b >> 16);
}

// ---------------- K1: X -> Xt (swizzled bf16 image) + pool partials ------------
// Grid (64,16), 512 threads. Tile = 64 p x 256 c. Barrier-free direct transpose
// (round-12 proven), ONE barrier, then bulk 16B writes of the LDS image to Xt.
__global__ __launch_bounds__(512, 4) void k_prep(const float* __restrict__ in,
                                                 float* __restrict__ partial,
                                                 unsigned short* __restrict__ Xt) {
    __shared__ unsigned short Bs[64 * 256];   // 32 KB swizzled image
    __shared__ float partS[C_][2];            // 2 KB per-c half-sums
    const int t  = threadIdx.x;
    const int pt = blockIdx.x;
    const int b  = blockIdx.y;
    const int p0 = pt * 64;
    const int lane = t & 63, w = t >> 6;
    const float* Xb = in + ((size_t)b * C_) * HW_ + p0;

    const int dc = (lane >> 4) * 2;        // 0,2,4,6
    const int pl = (lane & 15) * 2;        // 0..30
#pragma unroll
    for (int it = 0; it < 8; ++it) {
        const int u = it * 8 + w;          // wave-uniform
        const int c_oct  = u & 31;
        const int p_half = u >> 5;
        const int c = c_oct * 8 + dc;
        const int p = p_half * 32 + pl;
        const float* s = Xb + (size_t)c * HW_ + p;
        float2 v0 = *reinterpret_cast<const float2*>(s);        // (c,   p/p+1)
        float2 v1 = *reinterpret_cast<const float2*>(s + HW_);  // (c+1, p/p+1)
        unsigned int ue = (unsigned int)f2bf(v0.x) | ((unsigned int)f2bf(v1.x) << 16);
        unsigned int uo = (unsigned int)f2bf(v0.y) | ((unsigned int)f2bf(v1.y) << 16);
        const int cse = c_oct ^ (p & 7);
        const int cso = c_oct ^ ((p + 1) & 7);
        *reinterpret_cast<unsigned int*>(&Bs[p * 256 + cse * 8 + dc]) = ue;
        *reinterpret_cast<unsigned int*>(&Bs[(p + 1) * 256 + cso * 8 + dc]) = uo;
        // partial pooling: rows c and c+1, this unit's 32 p
        float s0 = v0.x + v0.y;
        float s1 = v1.x + v1.y;
        s0 += __shfl_xor(s0, 1, 64); s1 += __shfl_xor(s1, 1, 64);
        s0 += __shfl_xor(s0, 2, 64); s1 += __shfl_xor(s1, 2, 64);
        s0 += __shfl_xor(s0, 4, 64); s1 += __shfl_xor(s1, 4, 64);
        s0 += __shfl_xor(s0, 8, 64); s1 += __shfl_xor(s1, 8, 64);
        if ((lane & 15) == 0) {
            partS[c][p_half]     = s0;
            partS[c + 1][p_half] = s1;
        }
    }
    __syncthreads();
    if (t < C_)
        partial[(size_t)(b * C_ + t) * 64 + pt] = partS[t][0] + partS[t][1];
    // bulk write the swizzled image (verbatim, coalesced 16B)
    unsigned short* dst = Xt + ((size_t)(b * HW_ + p0)) * C_;
#pragma unroll
    for (int i = 0; i < 4; ++i) {
        const int off = i * 4096 + t * 8;
        *reinterpret_cast<ushort8v*>(dst + off) =
            *reinterpret_cast<const ushort8v*>(Bs + off);
    }
}

// ------- K2: pooled (from partials) -> gates -> Weff(+I) slice + biasE ---------
__global__ __launch_bounds__(256) void k_wg(const float* __restrict__ partial,
                                            const float* __restrict__ Wr,
                                            const float* __restrict__ br,
                                            const float* __restrict__ Wexp,
                                            const float* __restrict__ bexp,
                                            unsigned short* __restrict__ Weff,
                                            float* __restrict__ biasE) {
    __shared__ float pooledS[C_];      // 1 KB
    __shared__ float wrs[C_ * E_];     // 8 KB
    __shared__ float lgp[64];
    __shared__ float gL[E_];
    const int t = threadIdx.x;
    const int b = blockIdx.y, dblk = blockIdx.x;

    {
        const float4* p4 = reinterpret_cast<const float4*>(
            partial + (size_t)(b * C_ + t) * 64);
        float s = 0.f;
#pragma unroll
        for (int j = 0; j < 16; ++j) {
            float4 v = p4[j];
            s += v.x + v.y + v.z + v.w;
        }
        pooledS[t] = s * (1.0f / HW_);
    }
#pragma unroll
    for (int i = 0; i < 2; ++i)
        reinterpret_cast<float4*>(wrs)[t + i * 256] =
            reinterpret_cast<const float4*>(Wr)[t + i * 256];
    __syncthreads();
    if (t < 64) {
        const int e = t & 7, seg = t >> 3;
        float s = 0.f;
#pragma unroll
        for (int c = seg * 32; c < seg * 32 + 32; ++c)
            s += pooledS[c] * wrs[c * E_ + e];
        lgp[t] = s;
    }
    __syncthreads();
    if (t == 0) {
        float w[E_];
        float m = -1e30f;
#pragma unroll
        for (int e = 0; e < E_; ++e) {
            float s = br[e];
#pragma unroll
            for (int k = 0; k < 8; ++k) s += lgp[k * 8 + e];
            w[e] = s; m = fmaxf(m, s);
        }
        float sum = 0.f;
#pragma unroll
        for (int e = 0; e < E_; ++e) { w[e] = __expf(w[e] - m); sum += w[e]; }
        float inv = 1.f / sum;
#pragma unroll
        for (int e = 0; e < E_; ++e) w[e] *= inv;
        int i0 = 0;
#pragma unroll
        for (int e = 1; e < E_; ++e) if (w[e] > w[i0]) i0 = e;
        int i1 = -1;
#pragma unroll
        for (int e = 0; e < E_; ++e) {
            if (e == i0) continue;
            if (i1 < 0 || w[e] > w[i1]) i1 = e;
        }
#pragma unroll
        for (int e = 0; e < E_; ++e)
            gL[e] = (e == i0 || e == i1) ? w[e] : 0.f;
    }
    __syncthreads();
    if (dblk == 0) {
        float s = 0.f;
#pragma unroll
        for (int e = 0; e < E_; ++e) s += gL[e] * bexp[e * C_ + t];
        biasE[b * C_ + t] = s;
    }
    const int dloc = t >> 5, cq = t & 31;
    const int d = dblk * 8 + dloc;
#pragma unroll
    for (int half = 0; half < 2; half++) {
        const int c = (cq + half * 32) * 4;
        float4 a = {0.f, 0.f, 0.f, 0.f};
#pragma unroll
        for (int e = 0; e < E_; e++) {
            float ge = gL[e];
            if (ge != 0.f) {
                float4 wv = *reinterpret_cast<const float4*>(
                    Wexp + ((size_t)(e * C_ + d)) * C_ + c);
                a.x += ge * wv.x; a.y += ge * wv.y;
                a.z += ge * wv.z; a.w += ge * wv.w;
            }
        }
        // fold identity: W' = Weff + I
        const int diff = d - c;
        if (diff == 0) a.x += 1.f;
        else if (diff == 1) a.y += 1.f;
        else if (diff == 2) a.z += 1.f;
        else if (diff == 3) a.w += 1.f;
        ushort4v o = { f2bf(a.x), f2bf(a.y), f2bf(a.z), f2bf(a.w) };
        *reinterpret_cast<ushort4v*>(Weff + ((size_t)(b * C_ + d)) * C_ + c) = o;
    }
}

// ---------------- K3: out[b] = W'[b] @ x + biasE[b] — ZERO LDS, ZERO barriers --
// Grid (64,16), 512 threads (8 waves). B-fragments read DIRECTLY from the
// swizzled Xt image (L2/L3-resident 32KB tile, 8x in-block reuse); A from
// L2-resident Weff. Swapped-operand MFMA + float4 epilogue (round-12 proven).
__global__ __launch_bounds__(512, 8) void k_gemm(const unsigned short* __restrict__ Xt,
                                                 const unsigned short* __restrict__ Weff,
                                                 const float* __restrict__ biasE,
                                                 float* __restrict__ out) {
    const int t  = threadIdx.x;
    const int pt = blockIdx.x;
    const int b  = blockIdx.y;
    const int n0 = pt * 64;
    const int lane = t & 63, w = t >> 6;
    const int kg = lane >> 4, lr = lane & 15;
    const unsigned short* Ab  = Weff + (size_t)b * C_ * C_;
    const unsigned short* Xtb = Xt + ((size_t)(b * HW_ + n0)) * C_;

    // acc init: bias[d] splat
    f32x4 acc[2][4];
#pragma unroll
    for (int fd = 0; fd < 2; ++fd) {
        const float bias = biasE[b * C_ + w * 32 + fd * 16 + lr];
#pragma unroll
        for (int pf = 0; pf < 4; ++pf)
            acc[fd][pf] = (f32x4){bias, bias, bias, bias};
    }

    // MFMA loop: W-frags + X-frags both from cache (no staging, no barriers)
#pragma unroll
    for (int kf = 0; kf < 8; ++kf) {
        bf16x8 wf[2];
#pragma unroll
        for (int fd = 0; fd < 2; ++fd) {
            const int row = w * 32 + fd * 16 + lr;
            wf[fd] = __builtin_bit_cast(bf16x8,
                *reinterpret_cast<const ushort8v*>(
                    &Ab[(size_t)row * C_ + kf * 32 + kg * 8]));
        }
#pragma unroll
        for (int pf = 0; pf < 4; ++pf) {
            const int p = pf * 16 + lr;
            const int cc = (kf * 4 + kg) ^ (p & 7);
            bf16x8 xf = __builtin_bit_cast(bf16x8,
                *reinterpret_cast<const ushort8v*>(&Xtb[p * 256 + cc * 8]));
            acc[0][pf] = __builtin_amdgcn_mfma_f32_16x16x32_bf16(
                xf, wf[0], acc[0][pf], 0, 0, 0);
            acc[1][pf] = __builtin_amdgcn_mfma_f32_16x16x32_bf16(
                xf, wf[1], acc[1][pf], 0, 0, 0);
        }
    }

    // store: lane holds 4 consecutive p at one d -> float4
    float* outB = out + ((size_t)b * C_) * HW_ + n0;
#pragma unroll
    for (int fd = 0; fd < 2; ++fd) {
        const int row = w * 32 + fd * 16 + lr;
        float* orow = outB + (size_t)row * HW_;
#pragma unroll
        for (int pf = 0; pf < 4; ++pf) {
            *reinterpret_cast<f32x4*>(&orow[pf * 16 + kg * 4]) = acc[fd][pf];
        }
    }
}

extern "C" void kernel_launch(void* const* d_in, const int* in_sizes, int n_in,
                              void* d_out, int out_size, void* d_ws, size_t ws_size,
                              hipStream_t stream) {
    const float* in   = (const float*)d_in[0];
    const float* Wr   = (const float*)d_in[1];
    const float* br   = (const float*)d_in[2];
    const float* Wexp = (const float*)d_in[3];
    const float* bexp = (const float*)d_in[4];
    float* out = (float*)d_out;
    char* ws = (char*)d_ws;

    float* partial        = (float*)(ws);                      // 1 MB
    unsigned short* Weff  = (unsigned short*)(ws + 0x100000);  // 2 MB
    float* biasE          = (float*)(ws + 0x300000);           // 16 KB
    unsigned short* Xt    = (unsigned short*)(ws + 0x310000);  // 32 MB

    hipLaunchKernelGGL(k_prep, dim3(64, B_), dim3(512), 0, stream, in, partial, Xt);
    hipLaunchKernelGGL(k_wg,   dim3(32, B_), dim3(256), 0, stream,
                       partial, Wr, br, Wexp, bexp, Weff, biasE);
    hipLaunchKernelGGL(k_gemm, dim3(64, B_), dim3(512), 0, stream,
                       Xt, Weff, biasE, out);
}

// Round 15
// 54.483 us; speedup vs baseline: 1.4741x; 1.2340x over previous
//
#include <hip/hip_runtime.h>
#include <hip/hip_bf16.h>

typedef __bf16 bf16x8 __attribute__((ext_vector_type(8)));
typedef float f32x4 __attribute__((ext_vector_type(4)));
typedef unsigned short ushort4v __attribute__((ext_vector_type(4)));
typedef unsigned short ushort8v __attribute__((ext_vector_type(8)));

#define B_  16
#define C_  256
#define HW_ 4096
#define E_  8

__device__ inline unsigned short f2bf(float f) {
    unsigned int b = __builtin_bit_cast(unsigned int, f);
    b += 0x7FFFu + ((b >> 16) & 1u);   // RNE (inputs finite)
    return (unsigned short)(b >> 16);
}

// ------- K1: pooled[b][c] = mean_p X[b,c,p]  AND  Xbf = bf16(X) (same layout) --
__global__ __launch_bounds__(256) void k_pool(const float* __restrict__ in,
                                              float* __restrict__ pooled,
                                              unsigned short* __restrict__ Xbf) {
    int bc = blockIdx.x;
    const float* p = in + (size_t)bc * HW_;
    unsigned short* o = Xbf + (size_t)bc * HW_;
    int t = threadIdx.x;
    float s = 0.f;
#pragma unroll
    for (int i = 0; i < 4; i++) {
        const int off = (t + i * 256) * 4;
        float4 v = *reinterpret_cast<const float4*>(p + off);
        s += v.x + v.y + v.z + v.w;
        ushort4v u = { f2bf(v.x), f2bf(v.y), f2bf(v.z), f2bf(v.w) };
        *reinterpret_cast<ushort4v*>(o + off) = u;
    }
#pragma unroll
    for (int off = 32; off; off >>= 1) s += __shfl_down(s, off, 64);
    __shared__ float part[4];
    if ((t & 63) == 0) part[t >> 6] = s;
    __syncthreads();
    if (t == 0) pooled[bc] = (part[0] + part[1] + part[2] + part[3]) * (1.0f / HW_);
}

// ------- K2: gates + Weff slice (identity folded in) + biasE -------------------
__global__ __launch_bounds__(256) void k_wg(const float* __restrict__ pooled,
                                            const float* __restrict__ Wr,
                                            const float* __restrict__ br,
                                            const float* __restrict__ Wexp,
                                            const float* __restrict__ bexp,
                                            unsigned short* __restrict__ Weff,
                                            float* __restrict__ biasE) {
    __shared__ float pooledS[C_];      // 1 KB
    __shared__ float wrs[C_ * E_];     // 8 KB
    __shared__ float lgp[64];
    __shared__ float gL[E_];
    const int t = threadIdx.x;
    const int b = blockIdx.y, dblk = blockIdx.x;

    pooledS[t] = pooled[b * C_ + t];
#pragma unroll
    for (int i = 0; i < 2; ++i)
        reinterpret_cast<float4*>(wrs)[t + i * 256] =
            reinterpret_cast<const float4*>(Wr)[t + i * 256];
    __syncthreads();
    if (t < 64) {
        const int e = t & 7, seg = t >> 3;
        float s = 0.f;
#pragma unroll
        for (int c = seg * 32; c < seg * 32 + 32; ++c)
            s += pooledS[c] * wrs[c * E_ + e];
        lgp[t] = s;
    }
    __syncthreads();
    if (t == 0) {
        float w[E_];
        float m = -1e30f;
#pragma unroll
        for (int e = 0; e < E_; ++e) {
            float s = br[e];
#pragma unroll
            for (int k = 0; k < 8; ++k) s += lgp[k * 8 + e];
            w[e] = s; m = fmaxf(m, s);
        }
        float sum = 0.f;
#pragma unroll
        for (int e = 0; e < E_; ++e) { w[e] = __expf(w[e] - m); sum += w[e]; }
        float inv = 1.f / sum;
#pragma unroll
        for (int e = 0; e < E_; ++e) w[e] *= inv;
        int i0 = 0;
#pragma unroll
        for (int e = 1; e < E_; ++e) if (w[e] > w[i0]) i0 = e;
        int i1 = -1;
#pragma unroll
        for (int e = 0; e < E_; ++e) {
            if (e == i0) continue;
            if (i1 < 0 || w[e] > w[i1]) i1 = e;
        }
#pragma unroll
        for (int e = 0; e < E_; ++e)
            gL[e] = (e == i0 || e == i1) ? w[e] : 0.f;
    }
    __syncthreads();
    if (dblk == 0) {
        float s = 0.f;
#pragma unroll
        for (int e = 0; e < E_; ++e) s += gL[e] * bexp[e * C_ + t];
        biasE[b * C_ + t] = s;
    }
    const int dloc = t >> 5, cq = t & 31;
    const int d = dblk * 8 + dloc;
#pragma unroll
    for (int half = 0; half < 2; half++) {
        const int c = (cq + half * 32) * 4;
        float4 a = {0.f, 0.f, 0.f, 0.f};
#pragma unroll
        for (int e = 0; e < E_; e++) {
            float ge = gL[e];
            if (ge != 0.f) {
                float4 wv = *reinterpret_cast<const float4*>(
                    Wexp + ((size_t)(e * C_ + d)) * C_ + c);
                a.x += ge * wv.x; a.y += ge * wv.y;
                a.z += ge * wv.z; a.w += ge * wv.w;
            }
        }
        // fold identity: W' = Weff + I
        const int diff = d - c;
        if (diff == 0) a.x += 1.f;
        else if (diff == 1) a.y += 1.f;
        else if (diff == 2) a.z += 1.f;
        else if (diff == 3) a.w += 1.f;
        ushort4v o = { f2bf(a.x), f2bf(a.y), f2bf(a.z), f2bf(a.w) };
        *reinterpret_cast<ushort4v*>(Weff + ((size_t)(b * C_ + d)) * C_ + c) = o;
    }
}

// ---------------- K3: fused  out[b] = W'[b] @ x + biasE[b] ---------------------
// Round-12 structure; staging now reads the (L3-resident) bf16 copy of X and
// does the 2x2 transpose with bit ops. One barrier total. LDS 33 KB, 4 blk/CU.
__global__ __launch_bounds__(512, 8) void k_fused(const unsigned short* __restrict__ Xbf,
                                                  const unsigned short* __restrict__ Weff,
                                                  const float* __restrict__ biasE,
                                                  float* __restrict__ out) {
    __shared__ unsigned short Bs[64 * 256];   // 32 KB [p][c] bf16, chunk-XOR-swizzled
    __shared__ float biasS[C_];               // 1 KB

    const int t  = threadIdx.x;
    const int b  = blockIdx.y;
    const int n0 = blockIdx.x * 64;
    const int lane = t & 63, w = t >> 6;
    const int kg = lane >> 4, lr = lane & 15;
    const unsigned short* Xb = Xbf + ((size_t)b * C_) * HW_ + n0;
    const unsigned short* Ab = Weff + (size_t)b * C_ * C_;

    if (t < C_) biasS[t] = biasE[b * C_ + t];

    // ---- stage: 64 units of (8c x 32p); unit u = it*8 + w ----
    {
        const int dc = (lane >> 4) * 2;        // 0,2,4,6
        const int pl = (lane & 15) * 2;        // 0..30
#pragma unroll
        for (int it = 0; it < 8; ++it) {
            const int u = it * 8 + w;          // wave-uniform
            const int c_oct  = u & 31;         // logical chunk (c>>3)
            const int p_half = u >> 5;
            const int c = c_oct * 8 + dc;
            const int p = p_half * 32 + pl;
            const unsigned short* s = Xb + (size_t)c * HW_ + p;
            unsigned int v0 = *reinterpret_cast<const unsigned int*>(s);        // (c,p)|(c,p+1)
            unsigned int v1 = *reinterpret_cast<const unsigned int*>(s + HW_);  // (c+1,p)|(c+1,p+1)
            unsigned int ue = (v0 & 0xffffu) | (v1 << 16);          // (c,p),(c+1,p)
            unsigned int uo = (v0 >> 16) | (v1 & 0xffff0000u);      // (c,p+1),(c+1,p+1)
            const int cse = c_oct ^ (p & 7);
            const int cso = c_oct ^ ((p + 1) & 7);
            *reinterpret_cast<unsigned int*>(&Bs[p * 256 + cse * 8 + dc]) = ue;
            *reinterpret_cast<unsigned int*>(&Bs[(p + 1) * 256 + cso * 8 + dc]) = uo;
        }
    }
    __syncthreads();

    // ---- acc init: bias[d] splat (d = col = w*32 + fd*16 + lr) ----
    f32x4 acc[2][4];
#pragma unroll
    for (int fd = 0; fd < 2; ++fd) {
        const float bias = biasS[w * 32 + fd * 16 + lr];
#pragma unroll
        for (int pf = 0; pf < 4; ++pf)
            acc[fd][pf] = (f32x4){bias, bias, bias, bias};
    }

    // ---- MFMA main loop: 8 k-frags; W-frags from L2-resident Weff ----
#pragma unroll
    for (int kf = 0; kf < 8; ++kf) {
        bf16x8 wf[2];
#pragma unroll
        for (int fd = 0; fd < 2; ++fd) {
            const int row = w * 32 + fd * 16 + lr;
            wf[fd] = __builtin_bit_cast(bf16x8,
                *reinterpret_cast<const ushort8v*>(
                    &Ab[(size_t)row * C_ + kf * 32 + kg * 8]));
        }
#pragma unroll
        for (int pf = 0; pf < 4; ++pf) {
            const int p = pf * 16 + lr;
            const int cc = (kf * 4 + kg) ^ (p & 7);
            bf16x8 xf = __builtin_bit_cast(bf16x8,
                *reinterpret_cast<const ushort8v*>(&Bs[p * 256 + cc * 8]));
            acc[0][pf] = __builtin_amdgcn_mfma_f32_16x16x32_bf16(
                xf, wf[0], acc[0][pf], 0, 0, 0);
            acc[1][pf] = __builtin_amdgcn_mfma_f32_16x16x32_bf16(
                xf, wf[1], acc[1][pf], 0, 0, 0);
        }
    }

    // ---- store: lane holds 4 consecutive p at one d -> float4 ----
    float* outB = out + ((size_t)b * C_) * HW_ + n0;
#pragma unroll
    for (int fd = 0; fd < 2; ++fd) {
        const int row = w * 32 + fd * 16 + lr;
        float* orow = outB + (size_t)row * HW_;
#pragma unroll
        for (int pf = 0; pf < 4; ++pf) {
            *reinterpret_cast<f32x4*>(&orow[pf * 16 + kg * 4]) = acc[fd][pf];
        }
    }
}

extern "C" void kernel_launch(void* const* d_in, const int* in_sizes, int n_in,
                              void* d_out, int out_size, void* d_ws, size_t ws_size,
                              hipStream_t stream) {
    const float* in   = (const float*)d_in[0];
    const float* Wr   = (const float*)d_in[1];
    const float* br   = (const float*)d_in[2];
    const float* Wexp = (const float*)d_in[3];
    const float* bexp = (const float*)d_in[4];
    float* out = (float*)d_out;
    char* ws = (char*)d_ws;

    float* pooled         = (float*)(ws);                     // 16 KB
    float* biasE          = (float*)(ws + 0x11000);           // 16 KB
    unsigned short* Weff  = (unsigned short*)(ws + 0x20000);  // 2 MB
    unsigned short* Xbf   = (unsigned short*)(ws + 0x400000); // 32 MB

    hipLaunchKernelGGL(k_pool,  dim3(B_ * C_), dim3(256), 0, stream, in, pooled, Xbf);
    hipLaunchKernelGGL(k_wg,    dim3(32, B_),  dim3(256), 0, stream,
                       pooled, Wr, br, Wexp, bexp, Weff, biasE);
    hipLaunchKernelGGL(k_fused, dim3(HW_ / 64, B_), dim3(512), 0, stream,
                       Xbf, Weff, biasE, out);
}

// Round 16
// 53.258 us; speedup vs baseline: 1.5080x; 1.0230x over previous
//
#include <hip/hip_runtime.h>
#include <hip/hip_bf16.h>

typedef __bf16 bf16x8 __attribute__((ext_vector_type(8)));
typedef float f32x4 __attribute__((ext_vector_type(4)));
typedef unsigned short ushort4v __attribute__((ext_vector_type(4)));
typedef unsigned short ushort8v __attribute__((ext_vector_type(8)));

#define B_  16
#define C_  256
#define HW_ 4096
#define E_  8

__device__ inline unsigned short f2bf(float f) {
    unsigned int b = __builtin_bit_cast(unsigned int, f);
    b += 0x7FFFu + ((b >> 16) & 1u);   // RNE (inputs finite)
    return (unsigned short)(b >> 16);
}

// ---------------- K1: pooled[b][c] = mean_{h,w} inputs[b,c,h,w] ----------------
__global__ __launch_bounds__(256) void k_pool(const float* __restrict__ in,
                                              float* __restrict__ pooled) {
    int bc = blockIdx.x;
    const float* p = in + (size_t)bc * HW_;
    int t = threadIdx.x;
    float s = 0.f;
#pragma unroll
    for (int i = 0; i < 4; i++) {
        float4 v = *reinterpret_cast<const float4*>(p + (size_t)(t + i * 256) * 4);
        s += v.x + v.y + v.z + v.w;
    }
#pragma unroll
    for (int off = 32; off; off >>= 1) s += __shfl_down(s, off, 64);
    __shared__ float part[4];
    if ((t & 63) == 0) part[t >> 6] = s;
    __syncthreads();
    if (t == 0) pooled[bc] = (part[0] + part[1] + part[2] + part[3]) * (1.0f / HW_);
}

// ------- K2: gates + Weff slice (identity folded in) + biasE -------------------
__global__ __launch_bounds__(256) void k_wg(const float* __restrict__ pooled,
                                            const float* __restrict__ Wr,
                                            const float* __restrict__ br,
                                            const float* __restrict__ Wexp,
                                            const float* __restrict__ bexp,
                                            unsigned short* __restrict__ Weff,
                                            float* __restrict__ biasE) {
    __shared__ float pooledS[C_];      // 1 KB
    __shared__ float wrs[C_ * E_];     // 8 KB
    __shared__ float lgp[64];
    __shared__ float gL[E_];
    const int t = threadIdx.x;
    const int b = blockIdx.y, dblk = blockIdx.x;

    pooledS[t] = pooled[b * C_ + t];
#pragma unroll
    for (int i = 0; i < 2; ++i)
        reinterpret_cast<float4*>(wrs)[t + i * 256] =
            reinterpret_cast<const float4*>(Wr)[t + i * 256];
    __syncthreads();
    if (t < 64) {
        const int e = t & 7, seg = t >> 3;
        float s = 0.f;
#pragma unroll
        for (int c = seg * 32; c < seg * 32 + 32; ++c)
            s += pooledS[c] * wrs[c * E_ + e];
        lgp[t] = s;
    }
    __syncthreads();
    if (t == 0) {
        float w[E_];
        float m = -1e30f;
#pragma unroll
        for (int e = 0; e < E_; ++e) {
            float s = br[e];
#pragma unroll
            for (int k = 0; k < 8; ++k) s += lgp[k * 8 + e];
            w[e] = s; m = fmaxf(m, s);
        }
        float sum = 0.f;
#pragma unroll
        for (int e = 0; e < E_; ++e) { w[e] = __expf(w[e] - m); sum += w[e]; }
        float inv = 1.f / sum;
#pragma unroll
        for (int e = 0; e < E_; ++e) w[e] *= inv;
        int i0 = 0;
#pragma unroll
        for (int e = 1; e < E_; ++e) if (w[e] > w[i0]) i0 = e;
        int i1 = -1;
#pragma unroll
        for (int e = 0; e < E_; ++e) {
            if (e == i0) continue;
            if (i1 < 0 || w[e] > w[i1]) i1 = e;
        }
#pragma unroll
        for (int e = 0; e < E_; ++e)
            gL[e] = (e == i0 || e == i1) ? w[e] : 0.f;
    }
    __syncthreads();
    if (dblk == 0) {
        float s = 0.f;
#pragma unroll
        for (int e = 0; e < E_; ++e) s += gL[e] * bexp[e * C_ + t];
        biasE[b * C_ + t] = s;
    }
    const int dloc = t >> 5, cq = t & 31;
    const int d = dblk * 8 + dloc;
#pragma unroll
    for (int half = 0; half < 2; half++) {
        const int c = (cq + half * 32) * 4;
        float4 a = {0.f, 0.f, 0.f, 0.f};
#pragma unroll
        for (int e = 0; e < E_; e++) {
            float ge = gL[e];
            if (ge != 0.f) {
                float4 wv = *reinterpret_cast<const float4*>(
                    Wexp + ((size_t)(e * C_ + d)) * C_ + c);
                a.x += ge * wv.x; a.y += ge * wv.y;
                a.z += ge * wv.z; a.w += ge * wv.w;
            }
        }
        // fold identity: W' = Weff + I
        const int diff = d - c;
        if (diff == 0) a.x += 1.f;
        else if (diff == 1) a.y += 1.f;
        else if (diff == 2) a.z += 1.f;
        else if (diff == 3) a.w += 1.f;
        ushort4v o = { f2bf(a.x), f2bf(a.y), f2bf(a.z), f2bf(a.w) };
        *reinterpret_cast<ushort4v*>(Weff + ((size_t)(b * C_ + d)) * C_ + c) = o;
    }
}

// ---------------- K3: fused  out[b] = W'[b] @ x + biasE[b] ---------------------
// 512 threads (8 waves), N-tile 64, full K=256 in LDS (Bs, chunk-XOR-swizzled).
// Barrier-free direct-transpose staging (one barrier total); swapped-operand
// MFMA (lane holds 4 consecutive p at one d) -> float4 epilogue. LDS 33 KB.
__global__ __launch_bounds__(512, 8) void k_fused(const float* __restrict__ in,
                                                  const unsigned short* __restrict__ Weff,
                                                  const float* __restrict__ biasE,
                                                  float* __restrict__ out) {
    __shared__ unsigned short Bs[64 * 256];   // 32 KB [p][c] bf16, chunk-XOR-swizzled
    __shared__ float biasS[C_];               // 1 KB

    const int t  = threadIdx.x;
    const int b  = blockIdx.y;
    const int n0 = blockIdx.x * 64;
    const int lane = t & 63, w = t >> 6;
    const int kg = lane >> 4, lr = lane & 15;
    const float* Xb = in + ((size_t)b * C_) * HW_ + n0;
    const unsigned short* Ab = Weff + (size_t)b * C_ * C_;

    if (t < C_) biasS[t] = biasE[b * C_ + t];

    // ---- stage: 64 units of (8c x 32p); unit u = it*8 + w ----
    {
        const int dc = (lane >> 4) * 2;        // 0,2,4,6
        const int pl = (lane & 15) * 2;        // 0..30
#pragma unroll
        for (int it = 0; it < 8; ++it) {
            const int u = it * 8 + w;          // wave-uniform
            const int c_oct  = u & 31;         // logical chunk (c>>3)
            const int p_half = u >> 5;
            const int c = c_oct * 8 + dc;
            const int p = p_half * 32 + pl;
            const float* s = Xb + (size_t)c * HW_ + p;
            float2 v0 = *reinterpret_cast<const float2*>(s);        // (c, p/p+1)
            float2 v1 = *reinterpret_cast<const float2*>(s + HW_);  // (c+1, p/p+1)
            unsigned int ue = (unsigned int)f2bf(v0.x) | ((unsigned int)f2bf(v1.x) << 16);
            unsigned int uo = (unsigned int)f2bf(v0.y) | ((unsigned int)f2bf(v1.y) << 16);
            const int cse = c_oct ^ (p & 7);
            const int cso = c_oct ^ ((p + 1) & 7);
            *reinterpret_cast<unsigned int*>(&Bs[p * 256 + cse * 8 + dc]) = ue;
            *reinterpret_cast<unsigned int*>(&Bs[(p + 1) * 256 + cso * 8 + dc]) = uo;
        }
    }
    __syncthreads();

    // ---- acc init: bias[d] splat (d = col = w*32 + fd*16 + lr) ----
    f32x4 acc[2][4];
#pragma unroll
    for (int fd = 0; fd < 2; ++fd) {
        const float bias = biasS[w * 32 + fd * 16 + lr];
#pragma unroll
        for (int pf = 0; pf < 4; ++pf)
            acc[fd][pf] = (f32x4){bias, bias, bias, bias};
    }

    // ---- MFMA main loop: 8 k-frags; W-frags from L2-resident Weff ----
#pragma unroll
    for (int kf = 0; kf < 8; ++kf) {
        bf16x8 wf[2];
#pragma unroll
        for (int fd = 0; fd < 2; ++fd) {
            const int row = w * 32 + fd * 16 + lr;
            wf[fd] = __builtin_bit_cast(bf16x8,
                *reinterpret_cast<const ushort8v*>(
                    &Ab[(size_t)row * C_ + kf * 32 + kg * 8]));
        }
#pragma unroll
        for (int pf = 0; pf < 4; ++pf) {
            const int p = pf * 16 + lr;
            const int cc = (kf * 4 + kg) ^ (p & 7);
            bf16x8 xf = __builtin_bit_cast(bf16x8,
                *reinterpret_cast<const ushort8v*>(&Bs[p * 256 + cc * 8]));
            acc[0][pf] = __builtin_amdgcn_mfma_f32_16x16x32_bf16(
                xf, wf[0], acc[0][pf], 0, 0, 0);
            acc[1][pf] = __builtin_amdgcn_mfma_f32_16x16x32_bf16(
                xf, wf[1], acc[1][pf], 0, 0, 0);
        }
    }

    // ---- store: lane holds 4 consecutive p at one d -> float4 ----
    float* outB = out + ((size_t)b * C_) * HW_ + n0;
#pragma unroll
    for (int fd = 0; fd < 2; ++fd) {
        const int row = w * 32 + fd * 16 + lr;
        float* orow = outB + (size_t)row * HW_;
#pragma unroll
        for (int pf = 0; pf < 4; ++pf) {
            *reinterpret_cast<f32x4*>(&orow[pf * 16 + kg * 4]) = acc[fd][pf];
        }
    }
}

extern "C" void kernel_launch(void* const* d_in, const int* in_sizes, int n_in,
                              void* d_out, int out_size, void* d_ws, size_t ws_size,
                              hipStream_t stream) {
    const float* in   = (const float*)d_in[0];
    const float* Wr   = (const float*)d_in[1];
    const float* br   = (const float*)d_in[2];
    const float* Wexp = (const float*)d_in[3];
    const float* bexp = (const float*)d_in[4];
    float* out = (float*)d_out;
    char* ws = (char*)d_ws;

    float* pooled         = (float*)(ws);                    // 16 KB
    float* biasE          = (float*)(ws + 0x11000);          // 16 KB
    unsigned short* Weff  = (unsigned short*)(ws + 0x20000); // 2 MB

    hipLaunchKernelGGL(k_pool,  dim3(B_ * C_), dim3(256), 0, stream, in, pooled);
    hipLaunchKernelGGL(k_wg,    dim3(32, B_),  dim3(256), 0, stream,
                       pooled, Wr, br, Wexp, bexp, Weff, biasE);
    hipLaunchKernelGGL(k_fused, dim3(HW_ / 64, B_), dim3(512), 0, stream,
                       in, Weff, biasE, out);
}